// Round 1
// baseline (381.533 us; speedup 1.0000x reference)
//
#include <hip/hip_runtime.h>
#include <math.h>

// Problem constants (fixed by reference setup_inputs)
#define NG   8192      // groups
#define NS   64        // samples per group
#define ND   128       // feature dim
#define NH   256       // hidden dim
#define NO   10        // K+2 outputs of layer 2
#define GPB  16        // groups per block in MLP kernel
#define WPB  4         // waves per block in stats kernel

// native vector type: __builtin_nontemporal_load rejects HIP_vector_type
typedef float floatx4 __attribute__((ext_vector_type(4)));

// ---------------------------------------------------------------------------
// Kernel 1: per-group stats -> rep.  One wave per group, barrier-free.
// Raw-moment formulation: accumulate S=Σx, Sxy=Σx·y_rel, S2=Σx² and apply
// anchor corrections in closed form (anchor cancels exactly in cov).
// 4x8-deep nontemporal float4 load batches (was 2x16: same row order per
// lane -> bitwise-identical sums, ~32 fewer live VGPRs); shfl-only reduce.
// ---------------------------------------------------------------------------
__global__ __launch_bounds__(256) void stats_kernel(
    const float* __restrict__ x, const float* __restrict__ y,
    const float* __restrict__ ax, const float* __restrict__ ay,
    float* __restrict__ rep)
{
    const int t    = threadIdx.x;
    const int w    = t >> 6;          // wave within block
    const int l    = t & 63;          // lane
    const int g    = blockIdx.x * WPB + w;
    const int c    = l & 31;          // float4 column (dims 4c..4c+3)
    const int half = l >> 5;          // row half (0: rows 0-31, 1: rows 32-63)

    __shared__ float yrelL[WPB][NS];  // per-wave y_rel staging (wave-synchronous)

    float yv = y[g * NS + l] - ay[g];
    yrelL[w][l] = yv;                 // same wave writes & reads -> no barrier

    const floatx4 a4 = ((const floatx4*)ax)[g * 32 + c];
    const floatx4* xg = (const floatx4*)x
                      + (size_t)g * (NS * 32) + (size_t)(half * 32) * 32 + c;

    floatx4 S   = (floatx4)(0.f);     // Σ x          (per column)
    floatx4 Sxy = (floatx4)(0.f);     // Σ x * y_rel  (per column)
    float   S2  = 0.f;                // Σ x·x  (lane's 4 cols, 32 rows)

#pragma unroll
    for (int ii = 0; ii < 4; ++ii) {
        floatx4 xv[8];
#pragma unroll
        for (int j = 0; j < 8; ++j)
            xv[j] = __builtin_nontemporal_load(&xg[(ii * 8 + j) * 32]);
#pragma unroll
        for (int j = 0; j < 8; ++j) {
            const float yr = yrelL[w][half * 32 + ii * 8 + j];  // 2-addr bcast
            S   += xv[j];
            Sxy += xv[j] * yr;
            S2  += xv[j].x * xv[j].x + xv[j].y * xv[j].y
                 + xv[j].z * xv[j].z + xv[j].w * xv[j].w;
        }
    }

    // ---- per-lane anchor corrections (use pre-combine, 32-row raw S) ----
    // sxx_lane = Σ(x-a)² over lane's 32 rows × 4 cols
    float sxxc = S2 - 2.0f * (a4.x * S.x + a4.y * S.y + a4.z * S.z + a4.w * S.w)
               + 32.0f * (a4.x * a4.x + a4.y * a4.y + a4.z * a4.z + a4.w * a4.w);
    // tot_lane = Σ sx over lane's 4 cols (32 rows): (Σ S) - 32·(Σ a)
    float totc = (S.x + S.y + S.z + S.w) - 32.0f * (a4.x + a4.y + a4.z + a4.w);

    // ---- wave-wide scalar reductions (tot, sxx, sy): 64-lane butterflies ----
#pragma unroll
    for (int off = 32; off >= 1; off >>= 1) {
        totc += __shfl_xor(totc, off);
        sxxc += __shfl_xor(sxxc, off);
        yv   += __shfl_xor(yv,   off);      // becomes sy = Σ y_rel
    }

    // ---- combine row-halves for the per-column vectors ----
    S.x   += __shfl_xor(S.x,   32); S.y   += __shfl_xor(S.y,   32);
    S.z   += __shfl_xor(S.z,   32); S.w   += __shfl_xor(S.w,   32);
    Sxy.x += __shfl_xor(Sxy.x, 32); Sxy.y += __shfl_xor(Sxy.y, 32);
    Sxy.z += __shfl_xor(Sxy.z, 32); Sxy.w += __shfl_xor(Sxy.w, 32);

    // var = (sxx - tot²/(n·D)) / (n·D - 1)
    const float var = (sxxc - totc * totc * (1.0f / 8192.0f)) * (1.0f / 8191.0f);
    const float iv  = 1.0f / var;
    // cov = (Σx_rel·y_rel - sx·sy/n)/(n-1) = (Sxy - S·sy/n)/(n-1)  [anchor cancels]
    const float c0  = yv * (1.0f / 64.0f);
    floatx4 rp;
    rp.x = (Sxy.x - S.x * c0) * (1.0f / 63.0f) * iv;
    rp.y = (Sxy.y - S.y * c0) * (1.0f / 63.0f) * iv;
    rp.z = (Sxy.z - S.z * c0) * (1.0f / 63.0f) * iv;
    rp.w = (Sxy.w - S.w * c0) * (1.0f / 63.0f) * iv;
    if (half == 0) ((floatx4*)rep)[g * 32 + c] = rp;   // 512B coalesced store
}

// ---------------------------------------------------------------------------
// Kernel 2: MLP head.  512 blocks x 256 threads, GPB=16 groups per block.
// ---------------------------------------------------------------------------
__device__ __forceinline__ float fast_tanh(float v) {
    v = fminf(15.0f, fmaxf(-15.0f, v));
    float e = __expf(2.0f * v);
    return (e - 1.0f) / (e + 1.0f);
}

__device__ __forceinline__ float softplus_f(float v) {
    if (v > 15.0f) return v;
    return log1pf(__expf(v));
}

__global__ __launch_bounds__(256) void mlp_kernel(
    const float* __restrict__ rep, const float* __restrict__ W1,
    const float* __restrict__ b1, const float* __restrict__ W2,
    const float* __restrict__ b2, float* __restrict__ mix,
    float* __restrict__ scl, float* __restrict__ alp,
    float* __restrict__ bet)
{
    const int g0 = blockIdx.x * GPB;
    const int t = threadIdx.x;

    __shared__ __align__(16) float repL[GPB][ND];
    __shared__ float hL[GPB][NH + 1];     // +1 pad: kills 16-way bank conflict
    __shared__ float w2L[NH * NO];
    __shared__ float outL[GPB][NO];

    {
        const float4* rp4 = (const float4*)(rep + (size_t)g0 * ND);
        float4* dst = (float4*)&repL[0][0];
        dst[t] = rp4[t];
        dst[t + 256] = rp4[t + 256];
    }
    for (int i = t; i < NH * NO; i += 256) w2L[i] = W2[i];
    __syncthreads();

    float acc[GPB];
#pragma unroll
    for (int g = 0; g < GPB; ++g) acc[g] = 0.f;

    for (int d = 0; d < ND; d += 4) {
        float w0 = W1[(d + 0) * NH + t];
        float w1 = W1[(d + 1) * NH + t];
        float w2 = W1[(d + 2) * NH + t];
        float w3 = W1[(d + 3) * NH + t];
#pragma unroll
        for (int g = 0; g < GPB; ++g) {
            const float4 r4 = *(const float4*)&repL[g][d];   // wave-uniform broadcast
            acc[g] += r4.x * w0 + r4.y * w1 + r4.z * w2 + r4.w * w3;
        }
    }
    const float bb = b1[t];
#pragma unroll
    for (int g = 0; g < GPB; ++g) {
        hL[g][t] = fast_tanh(acc[g] + bb);
    }
    __syncthreads();

    if (t < GPB * NO) {
        const int g = t / NO;
        const int k = t - g * NO;
        float s = b2[k];
#pragma unroll 8
        for (int j = 0; j < NH; ++j) s += hL[g][j] * w2L[j * NO + k];
        outL[g][k] = s;
    }
    __syncthreads();

    if (t < GPB) {
        const int gg = g0 + t;
        float al = softplus_f(outL[t][0]) * 0.99f + 0.01f;
        float be = softplus_f(outL[t][1]) * 0.99f + 0.01f;
        float m = -1e30f;
#pragma unroll
        for (int k = 0; k < 8; ++k) m = fmaxf(m, outL[t][2 + k]);
        float e[8];
        float sum = 0.f;
#pragma unroll
        for (int k = 0; k < 8; ++k) { e[k] = __expf(outL[t][2 + k] - m); sum += e[k]; }
        float inv = 1.0f / sum;
#pragma unroll
        for (int k = 0; k < 8; ++k) mix[gg * 8 + k] = e[k] * inv;
        alp[gg] = al;
        bet[gg] = be;
        scl[gg] = sqrtf(be / al);
    }
}

// ---------------------------------------------------------------------------
extern "C" void kernel_launch(void* const* d_in, const int* in_sizes, int n_in,
                              void* d_out, int out_size, void* d_ws, size_t ws_size,
                              hipStream_t stream) {
    // inputs: 0=index (unused: groups are contiguous, 64 each), 1=x, 2=y,
    // 3=anchor_x, 4=anchor_y, 5=W1, 6=b1, 7=W2, 8=b2
    const float* x  = (const float*)d_in[1];
    const float* y  = (const float*)d_in[2];
    const float* ax = (const float*)d_in[3];
    const float* ay = (const float*)d_in[4];
    const float* W1 = (const float*)d_in[5];
    const float* b1 = (const float*)d_in[6];
    const float* W2 = (const float*)d_in[7];
    const float* b2 = (const float*)d_in[8];

    float* out = (float*)d_out;
    float* rep = out;                               // [G,128]
    float* mix = out + (size_t)NG * ND;             // [G,8]
    float* scl = mix + (size_t)NG * 8;              // [G,1]
    float* alp = scl + NG;                          // [G,1]
    float* bet = alp + NG;                          // [G,1]

    stats_kernel<<<NG / WPB, 256, 0, stream>>>(x, y, ax, ay, rep);
    mlp_kernel<<<NG / GPB, 256, 0, stream>>>(rep, W1, b1, W2, b2, mix, scl, alp, bet);
}

// Round 2
// 379.954 us; speedup vs baseline: 1.0042x; 1.0042x over previous
//
#include <hip/hip_runtime.h>
#include <math.h>

// Problem constants (fixed by reference setup_inputs)
#define NG   8192      // groups
#define NS   64        // samples per group
#define ND   128       // feature dim
#define NH   256       // hidden dim
#define NO   10        // K+2 outputs of layer 2
#define WPB  4         // waves (=groups) per block

// native vector type: __builtin_nontemporal_load rejects HIP_vector_type
typedef float floatx4 __attribute__((ext_vector_type(4)));

__device__ __forceinline__ float fast_tanh(float v) {
    v = fminf(15.0f, fmaxf(-15.0f, v));
    float e = __expf(2.0f * v);
    return (e - 1.0f) / (e + 1.0f);
}

__device__ __forceinline__ float softplus_f(float v) {
    if (v > 15.0f) return v;
    return log1pf(__expf(v));
}

// ---------------------------------------------------------------------------
// Fully fused kernel: stats -> rep -> MLP head.  2048 blocks x 256 threads,
// one wave per group for stats (barrier-free raw-moment formulation), then
// block-cooperative MLP: W1 is read exactly ONCE per block (wave w computes
// hidden units [64w,64w+64) for all 4 groups), layer 2 via per-wave butterfly.
// Removes: 2nd kernel launch, rep re-read (4.2 MB), per-block W1/W2 LDS
// staging of the old mlp kernel.
// ---------------------------------------------------------------------------
__global__ __launch_bounds__(256) void fused_kernel(
    const float* __restrict__ x, const float* __restrict__ y,
    const float* __restrict__ ax, const float* __restrict__ ay,
    const float* __restrict__ W1, const float* __restrict__ b1,
    const float* __restrict__ W2, const float* __restrict__ b2,
    float* __restrict__ rep, float* __restrict__ mix,
    float* __restrict__ scl, float* __restrict__ alp,
    float* __restrict__ bet)
{
    const int t    = threadIdx.x;
    const int w    = t >> 6;          // wave within block
    const int l    = t & 63;          // lane
    const int g    = blockIdx.x * WPB + w;
    const int c    = l & 31;          // float4 column (dims 4c..4c+3)
    const int half = l >> 5;          // row half (0: rows 0-31, 1: rows 32-63)

    __shared__ float yrelL[WPB][NS];              // per-wave y_rel staging
    __shared__ __align__(16) float repL[WPB][ND]; // per-group rep for MLP
    __shared__ float hL[WPB][NH];                 // hidden activations

    // ---------------- Phase A: per-group stats (one wave per group) --------
    float yv = y[g * NS + l] - ay[g];
    yrelL[w][l] = yv;                 // same wave writes & reads -> no barrier

    const floatx4 a4 = ((const floatx4*)ax)[g * 32 + c];
    const floatx4* xg = (const floatx4*)x
                      + (size_t)g * (NS * 32) + (size_t)(half * 32) * 32 + c;

    floatx4 S   = (floatx4)(0.f);     // Σ x          (per column)
    floatx4 Sxy = (floatx4)(0.f);     // Σ x * y_rel  (per column)
    float   S2  = 0.f;                // Σ x·x  (lane's 4 cols, 32 rows)

#pragma unroll
    for (int ii = 0; ii < 4; ++ii) {
        floatx4 xv[8];
#pragma unroll
        for (int j = 0; j < 8; ++j)
            xv[j] = __builtin_nontemporal_load(&xg[(ii * 8 + j) * 32]);
#pragma unroll
        for (int j = 0; j < 8; ++j) {
            const float yr = yrelL[w][half * 32 + ii * 8 + j];  // 2-addr bcast
            S   += xv[j];
            Sxy += xv[j] * yr;
            S2  += xv[j].x * xv[j].x + xv[j].y * xv[j].y
                 + xv[j].z * xv[j].z + xv[j].w * xv[j].w;
        }
    }

    // per-lane anchor corrections (pre-combine, 32-row raw S)
    float sxxc = S2 - 2.0f * (a4.x * S.x + a4.y * S.y + a4.z * S.z + a4.w * S.w)
               + 32.0f * (a4.x * a4.x + a4.y * a4.y + a4.z * a4.z + a4.w * a4.w);
    float totc = (S.x + S.y + S.z + S.w) - 32.0f * (a4.x + a4.y + a4.z + a4.w);

    // wave-wide scalar reductions (tot, sxx, sy)
#pragma unroll
    for (int off = 32; off >= 1; off >>= 1) {
        totc += __shfl_xor(totc, off);
        sxxc += __shfl_xor(sxxc, off);
        yv   += __shfl_xor(yv,   off);      // becomes sy = Σ y_rel
    }

    // combine row-halves for the per-column vectors
    S.x   += __shfl_xor(S.x,   32); S.y   += __shfl_xor(S.y,   32);
    S.z   += __shfl_xor(S.z,   32); S.w   += __shfl_xor(S.w,   32);
    Sxy.x += __shfl_xor(Sxy.x, 32); Sxy.y += __shfl_xor(Sxy.y, 32);
    Sxy.z += __shfl_xor(Sxy.z, 32); Sxy.w += __shfl_xor(Sxy.w, 32);

    const float var = (sxxc - totc * totc * (1.0f / 8192.0f)) * (1.0f / 8191.0f);
    const float iv  = 1.0f / var;
    const float c0  = yv * (1.0f / 64.0f);
    floatx4 rp;
    rp.x = (Sxy.x - S.x * c0) * (1.0f / 63.0f) * iv;
    rp.y = (Sxy.y - S.y * c0) * (1.0f / 63.0f) * iv;
    rp.z = (Sxy.z - S.z * c0) * (1.0f / 63.0f) * iv;
    rp.w = (Sxy.w - S.w * c0) * (1.0f / 63.0f) * iv;
    if (half == 0) {
        ((floatx4*)rep)[g * 32 + c] = rp;          // 512B coalesced store
        ((floatx4*)&repL[w][0])[c]  = rp;          // stage for MLP
    }
    __syncthreads();

    // ---------------- Phase B: hidden layer, W1 read once per block --------
    // wave w computes h[j], j = 64w + l, for ALL 4 groups in the block.
    {
        const int j = (w << 6) + l;
        float acc0 = 0.f, acc1 = 0.f, acc2 = 0.f, acc3 = 0.f;
        const floatx4* rl0 = (const floatx4*)&repL[0][0];
        const floatx4* rl1 = (const floatx4*)&repL[1][0];
        const floatx4* rl2 = (const floatx4*)&repL[2][0];
        const floatx4* rl3 = (const floatx4*)&repL[3][0];
#pragma unroll 8
        for (int d4 = 0; d4 < 32; ++d4) {
            const float w0  = W1[(4 * d4 + 0) * NH + j];   // coalesced 256B/instr
            const float w1v = W1[(4 * d4 + 1) * NH + j];
            const float w2v = W1[(4 * d4 + 2) * NH + j];
            const float w3v = W1[(4 * d4 + 3) * NH + j];
            floatx4 r;
            r = rl0[d4]; acc0 += r.x * w0 + r.y * w1v + r.z * w2v + r.w * w3v;
            r = rl1[d4]; acc1 += r.x * w0 + r.y * w1v + r.z * w2v + r.w * w3v;
            r = rl2[d4]; acc2 += r.x * w0 + r.y * w1v + r.z * w2v + r.w * w3v;
            r = rl3[d4]; acc3 += r.x * w0 + r.y * w1v + r.z * w2v + r.w * w3v;
        }
        const float bb = b1[j];
        hL[0][j] = fast_tanh(acc0 + bb);
        hL[1][j] = fast_tanh(acc1 + bb);
        hL[2][j] = fast_tanh(acc2 + bb);
        hL[3][j] = fast_tanh(acc3 + bb);
    }
    __syncthreads();

    // ---------------- Phase C: layer 2 + head, wave w -> its own group -----
    {
        float s[NO];
#pragma unroll
        for (int k = 0; k < NO; ++k) s[k] = 0.f;
#pragma unroll
        for (int u = 0; u < 4; ++u) {
            const int j = l + (u << 6);
            const float hv = hL[w][j];                 // 2-way bank: free
            const float* w2row = &W2[j * NO];          // L1/L2-hot (10 KB)
#pragma unroll
            for (int k = 0; k < NO; ++k) s[k] += hv * w2row[k];
        }
        // butterfly-reduce the 10 partial sums across the wave
#pragma unroll
        for (int k = 0; k < NO; ++k) {
#pragma unroll
            for (int off = 32; off >= 1; off >>= 1)
                s[k] += __shfl_xor(s[k], off);
        }
        if (l == 0) {
            float o[NO];
#pragma unroll
            for (int k = 0; k < NO; ++k) o[k] = s[k] + b2[k];
            const float al = softplus_f(o[0]) * 0.99f + 0.01f;
            const float be = softplus_f(o[1]) * 0.99f + 0.01f;
            float m = -1e30f;
#pragma unroll
            for (int k = 0; k < 8; ++k) m = fmaxf(m, o[2 + k]);
            float e[8];
            float sum = 0.f;
#pragma unroll
            for (int k = 0; k < 8; ++k) { e[k] = __expf(o[2 + k] - m); sum += e[k]; }
            const float inv = 1.0f / sum;
#pragma unroll
            for (int k = 0; k < 8; ++k) mix[g * 8 + k] = e[k] * inv;
            alp[g] = al;
            bet[g] = be;
            scl[g] = sqrtf(be / al);
        }
    }
}

// ---------------------------------------------------------------------------
extern "C" void kernel_launch(void* const* d_in, const int* in_sizes, int n_in,
                              void* d_out, int out_size, void* d_ws, size_t ws_size,
                              hipStream_t stream) {
    // inputs: 0=index (unused: groups are contiguous, 64 each), 1=x, 2=y,
    // 3=anchor_x, 4=anchor_y, 5=W1, 6=b1, 7=W2, 8=b2
    const float* x  = (const float*)d_in[1];
    const float* y  = (const float*)d_in[2];
    const float* ax = (const float*)d_in[3];
    const float* ay = (const float*)d_in[4];
    const float* W1 = (const float*)d_in[5];
    const float* b1 = (const float*)d_in[6];
    const float* W2 = (const float*)d_in[7];
    const float* b2 = (const float*)d_in[8];

    float* out = (float*)d_out;
    float* rep = out;                               // [G,128]
    float* mix = out + (size_t)NG * ND;             // [G,8]
    float* scl = mix + (size_t)NG * 8;              // [G,1]
    float* alp = scl + NG;                          // [G,1]
    float* bet = alp + NG;                          // [G,1]

    fused_kernel<<<NG / WPB, 256, 0, stream>>>(x, y, ax, ay, W1, b1, W2, b2,
                                               rep, mix, scl, alp, bet);
}